// Round 1
// baseline (112.144 us; speedup 1.0000x reference)
//
#include <hip/hip_runtime.h>
#include <cstddef>

// ---------------------------------------------------------------------------
// JPEG blockwise 8x8 DCT + quantization.
//   image:          [16, 1, 1024, 1024] fp32
//   quality_factor: [16] fp32
//   out:            [16, 64, 128, 128] fp32, channel c = u*8+v
//
// R5: keep R4's load/compute core (AAN scaled DCT, scales folded into
// registers), but replace the 64 scattered dword stores per thread with a
// 32 KiB LDS transpose + cooperative float4 stores:
//   - WG (256 thr) covers exactly 2 block-rows (i, i+1) of one batch image.
//   - Phase A: threads 0-127 write their 64 scaled coeffs to lds[c][j]
//     (consecutive-j per instr -> conflict-free), barrier, then ALL 256
//     threads store 8x float4 each: one wave instr = two dense 512 B
//     segments of a (c,i) output row. Phase B: same for the second row.
//   - Store instrs/thread: 64 dword -> 8 dwordx4. LDS 32 KiB keeps 4 WG/CU.
// Roofline: 64 MB in + 64 MB out => ~20 us at 6.3 TB/s; VALU ~11 us.
// ---------------------------------------------------------------------------

static constexpr double LUMQ[64] = {
    16, 11, 10, 16, 24, 40, 51, 61,
    12, 12, 14, 19, 26, 58, 60, 55,
    14, 13, 16, 24, 40, 57, 69, 56,
    14, 17, 22, 29, 51, 87, 80, 62,
    18, 22, 37, 56, 68, 109, 103, 77,
    24, 36, 55, 64, 81, 104, 113, 92,
    49, 64, 78, 87, 103, 121, 120, 101,
    72, 92, 95, 98, 112, 100, 103, 99,
};

// AAN per-coefficient scale: sqrt(2)*cos(k*pi/16), k=1..7; 1.0 for k=0.
static constexpr double AANS[8] = {
    1.0, 1.3870398453221475, 1.3065629648763766, 1.1758756024193588,
    1.0, 0.7856949583871022, 0.5411961001461970, 0.2758993792829430,
};

// Reference divides by Q = LUMQ/100; AAN raw 2D output is
// 8*aans[u]*aans[v] times the orthonormal DCT. Fold both (compile-time).
__device__ __host__ __forceinline__ constexpr float outScale(int u, int v) {
    return (float)(100.0 / (LUMQ[u * 8 + v] * 8.0 * AANS[u] * AANS[v]));
}

// AAN 8-point scaled forward DCT (jfdctflt.c flowgraph).
// In-place; output k is the true orthonormal DCT * sqrt(8) * aans[k].
__device__ __forceinline__ void aan_dct8(float& x0, float& x1, float& x2,
                                         float& x3, float& x4, float& x5,
                                         float& x6, float& x7) {
    const float t0 = x0 + x7, t7 = x0 - x7;
    const float t1 = x1 + x6, t6 = x1 - x6;
    const float t2 = x2 + x5, t5 = x2 - x5;
    const float t3 = x3 + x4, t4 = x3 - x4;

    // Even part
    float t10 = t0 + t3;
    const float t13 = t0 - t3;
    const float t11 = t1 + t2;
    const float t12 = t1 - t2;
    x0 = t10 + t11;
    x4 = t10 - t11;
    const float z1 = (t12 + t13) * 0.70710678118654752f;
    x2 = t13 + z1;
    x6 = t13 - z1;

    // Odd part
    t10 = t4 + t5;
    const float u11 = t5 + t6;
    const float u12 = t6 + t7;
    const float z5 = (t10 - u12) * 0.38268343236508977f;
    const float z2 = 0.54119610014619698f * t10 + z5;
    const float z4 = 1.30656296487637653f * u12 + z5;
    const float z3 = u11 * 0.70710678118654752f;
    const float z11 = t7 + z3;
    const float z13 = t7 - z3;
    x5 = z13 + z2;
    x3 = z13 - z2;
    x1 = z11 + z4;
    x7 = z11 - z4;
}

// Cooperative float4 store of one full block-row (all 64 planes, 128 j)
// from lds[c][j]. irow = global row index in [0, 2048): b = irow>>7,
// i = irow&127. Wave instr k: lanes cover c = k*8 + (tid>>5), jj=(tid&31)*4
// -> two dense 512 B segments per instruction.
__device__ __forceinline__ void store_row(float* __restrict__ out,
                                          const float* __restrict__ lds,
                                          int irow, int tid) {
    const int jj = (tid & 31) << 2;
    const int cbase = tid >> 5;                 // 0..7
    float* dst = out + ((size_t)(irow >> 7) << 20) + (size_t)(irow & 127) * 128 + jj;
    #pragma unroll
    for (int k = 0; k < 8; ++k) {
        const int c = (k << 3) + cbase;
        *reinterpret_cast<float4*>(dst + (size_t)c * 16384) =
            *reinterpret_cast<const float4*>(lds + c * 128 + jj);
    }
}

__global__ __launch_bounds__(256) void jpeg_dct_quant_kernel(
    const float* __restrict__ img,   // [16,1,1024,1024]
    const float* __restrict__ qfv,   // [16]
    float* __restrict__ out)         // [16,64,128,128]
{
    __shared__ float lds[64 * 128];  // [c][j] for one block-row, 32 KiB

    const int tid = threadIdx.x;
    const int wg = blockIdx.x;
    const int bid = wg * 256 + tid;   // global 8x8-block id
    const int j = bid & 127;          // block col
    const int irow = bid >> 7;        // global block-row in [0, 2048)
    const int b = bid >> 14;          // batch (uniform within WG)

    const float* src = img + ((size_t)b << 20)
                     + (size_t)((irow & 127) * 8) * 1024 + j * 8;

    // Load the full 8x8 block first (MLP = 16 outstanding float4 loads).
    float m[8][8];
    #pragma unroll
    for (int n = 0; n < 8; ++n) {
        const float4 r0 = *reinterpret_cast<const float4*>(src + (size_t)n * 1024);
        const float4 r1 = *reinterpret_cast<const float4*>(src + (size_t)n * 1024 + 4);
        m[n][0] = r0.x; m[n][1] = r0.y; m[n][2] = r0.z; m[n][3] = r0.w;
        m[n][4] = r1.x; m[n][5] = r1.y; m[n][6] = r1.z; m[n][7] = r1.w;
    }

    // Row pass (along columns within each row).
    #pragma unroll
    for (int n = 0; n < 8; ++n)
        aan_dct8(m[n][0], m[n][1], m[n][2], m[n][3],
                 m[n][4], m[n][5], m[n][6], m[n][7]);

    // Column pass.
    #pragma unroll
    for (int v = 0; v < 8; ++v)
        aan_dct8(m[0][v], m[1][v], m[2][v], m[3][v],
                 m[4][v], m[5][v], m[6][v], m[7][v]);

    // -128 centering only affects the raw DC term: 128*64 = 8192.
    m[0][0] -= 8192.0f;

    const float qf = qfv[b];
    const float factor = (qf < 50.0f) ? (5000.0f / qf) : (200.0f - 2.0f * qf);
    const float invf = 1.0f / factor;

    // Fold quant scale into registers before the LDS transpose.
    #pragma unroll
    for (int u = 0; u < 8; ++u)
        #pragma unroll
        for (int v = 0; v < 8; ++v)
            m[u][v] *= invf * outScale(u, v);

    // WG covers block-rows irowA = 2*wg (threads 0-127) and irowA+1
    // (threads 128-255); both share the same batch b.
    const int irowA = wg << 1;

    // Phase A: first row's coeffs -> LDS, then cooperative float4 stores.
    if (tid < 128) {
        #pragma unroll
        for (int u = 0; u < 8; ++u)
            #pragma unroll
            for (int v = 0; v < 8; ++v)
                lds[(u * 8 + v) * 128 + j] = m[u][v];
    }
    __syncthreads();
    store_row(out, lds, irowA, tid);
    __syncthreads();

    // Phase B: second row.
    if (tid >= 128) {
        #pragma unroll
        for (int u = 0; u < 8; ++u)
            #pragma unroll
            for (int v = 0; v < 8; ++v)
                lds[(u * 8 + v) * 128 + j] = m[u][v];
    }
    __syncthreads();
    store_row(out, lds, irowA + 1, tid);
}

extern "C" void kernel_launch(void* const* d_in, const int* in_sizes, int n_in,
                              void* d_out, int out_size, void* d_ws, size_t ws_size,
                              hipStream_t stream) {
    const float* img = (const float*)d_in[0];   // 16*1024*1024 fp32
    const float* qfv = (const float*)d_in[1];   // 16 fp32
    float* out = (float*)d_out;                 // 16*64*128*128 fp32

    // 16*128*128 = 262144 blocks, one thread each; 256 threads/WG -> 1024 WGs.
    jpeg_dct_quant_kernel<<<1024, 256, 0, stream>>>(img, qfv, out);
}

// Round 2
// 111.973 us; speedup vs baseline: 1.0015x; 1.0015x over previous
//
#include <hip/hip_runtime.h>
#include <cstddef>

// ---------------------------------------------------------------------------
// JPEG blockwise 8x8 DCT + quantization.
//   image:          [16, 1, 1024, 1024] fp32
//   quality_factor: [16] fp32
//   out:            [16, 64, 128, 128] fp32, channel c = u*8+v
//
// R6: isolate HBM write-burst granularity. R4 (scattered dwords) == R5
// (LDS + 512 B-segment float4 stores) == 112 us, so store instr count is
// not the bottleneck; the invariant is 512 B write segments. Out[b][c][i][j]
// has i-stride 512 B, and each WG owns two ADJACENT block-rows (i0, i0+1),
// so (c, i0, *) ++ (c, i0+1, *) is 1 KiB contiguous. Stage BOTH rows for
// 32 c-planes at a time in the same 32 KiB LDS (2 phases): each wave store
// instr becomes ONE dense 1 KiB burst (64 lanes x 16 B) instead of two
// 512 B segments. Everything else (reads, DCT, LDS bytes, barrier count,
// occupancy) identical to R5 -> clean A/B on burst length.
// Roofline: 64 MB in + 64 MB out => ~20 us at 6.3 TB/s; VALU ~2 us.
// ---------------------------------------------------------------------------

static constexpr double LUMQ[64] = {
    16, 11, 10, 16, 24, 40, 51, 61,
    12, 12, 14, 19, 26, 58, 60, 55,
    14, 13, 16, 24, 40, 57, 69, 56,
    14, 17, 22, 29, 51, 87, 80, 62,
    18, 22, 37, 56, 68, 109, 103, 77,
    24, 36, 55, 64, 81, 104, 113, 92,
    49, 64, 78, 87, 103, 121, 120, 101,
    72, 92, 95, 98, 112, 100, 103, 99,
};

// AAN per-coefficient scale: sqrt(2)*cos(k*pi/16), k=1..7; 1.0 for k=0.
static constexpr double AANS[8] = {
    1.0, 1.3870398453221475, 1.3065629648763766, 1.1758756024193588,
    1.0, 0.7856949583871022, 0.5411961001461970, 0.2758993792829430,
};

// Reference divides by Q = LUMQ/100; AAN raw 2D output is
// 8*aans[u]*aans[v] times the orthonormal DCT. Fold both (compile-time).
__device__ __host__ __forceinline__ constexpr float outScale(int u, int v) {
    return (float)(100.0 / (LUMQ[u * 8 + v] * 8.0 * AANS[u] * AANS[v]));
}

// AAN 8-point scaled forward DCT (jfdctflt.c flowgraph).
// In-place; output k is the true orthonormal DCT * sqrt(8) * aans[k].
__device__ __forceinline__ void aan_dct8(float& x0, float& x1, float& x2,
                                         float& x3, float& x4, float& x5,
                                         float& x6, float& x7) {
    const float t0 = x0 + x7, t7 = x0 - x7;
    const float t1 = x1 + x6, t6 = x1 - x6;
    const float t2 = x2 + x5, t5 = x2 - x5;
    const float t3 = x3 + x4, t4 = x3 - x4;

    // Even part
    float t10 = t0 + t3;
    const float t13 = t0 - t3;
    const float t11 = t1 + t2;
    const float t12 = t1 - t2;
    x0 = t10 + t11;
    x4 = t10 - t11;
    const float z1 = (t12 + t13) * 0.70710678118654752f;
    x2 = t13 + z1;
    x6 = t13 - z1;

    // Odd part
    t10 = t4 + t5;
    const float u11 = t5 + t6;
    const float u12 = t6 + t7;
    const float z5 = (t10 - u12) * 0.38268343236508977f;
    const float z2 = 0.54119610014619698f * t10 + z5;
    const float z4 = 1.30656296487637653f * u12 + z5;
    const float z3 = u11 * 0.70710678118654752f;
    const float z11 = t7 + z3;
    const float z13 = t7 - z3;
    x5 = z13 + z2;
    x3 = z13 - z2;
    x1 = z11 + z4;
    x7 = z11 - z4;
}

__global__ __launch_bounds__(256) void jpeg_dct_quant_kernel(
    const float* __restrict__ img,   // [16,1,1024,1024]
    const float* __restrict__ qfv,   // [16]
    float* __restrict__ out)         // [16,64,128,128]
{
    // [c_local 0..31][a 0..1][j 0..127]: 32 planes x BOTH block-rows, 32 KiB.
    __shared__ float lds[32 * 256];

    const int tid = threadIdx.x;
    const int wg = blockIdx.x;
    const int bid = wg * 256 + tid;   // global 8x8-block id
    const int j = bid & 127;          // block col
    const int irow = bid >> 7;        // global block-row in [0, 2048)
    const int b = bid >> 14;          // batch (uniform within WG)

    const float* src = img + ((size_t)b << 20)
                     + (size_t)((irow & 127) * 8) * 1024 + j * 8;

    // Load the full 8x8 block first (MLP = 16 outstanding float4 loads).
    float m[8][8];
    #pragma unroll
    for (int n = 0; n < 8; ++n) {
        const float4 r0 = *reinterpret_cast<const float4*>(src + (size_t)n * 1024);
        const float4 r1 = *reinterpret_cast<const float4*>(src + (size_t)n * 1024 + 4);
        m[n][0] = r0.x; m[n][1] = r0.y; m[n][2] = r0.z; m[n][3] = r0.w;
        m[n][4] = r1.x; m[n][5] = r1.y; m[n][6] = r1.z; m[n][7] = r1.w;
    }

    // Row pass (along columns within each row).
    #pragma unroll
    for (int n = 0; n < 8; ++n)
        aan_dct8(m[n][0], m[n][1], m[n][2], m[n][3],
                 m[n][4], m[n][5], m[n][6], m[n][7]);

    // Column pass.
    #pragma unroll
    for (int v = 0; v < 8; ++v)
        aan_dct8(m[0][v], m[1][v], m[2][v], m[3][v],
                 m[4][v], m[5][v], m[6][v], m[7][v]);

    // -128 centering only affects the raw DC term: 128*64 = 8192.
    m[0][0] -= 8192.0f;

    const float qf = qfv[b];
    const float factor = (qf < 50.0f) ? (5000.0f / qf) : (200.0f - 2.0f * qf);
    const float invf = 1.0f / factor;

    // Fold quant scale into registers before the LDS transpose.
    #pragma unroll
    for (int u = 0; u < 8; ++u)
        #pragma unroll
        for (int v = 0; v < 8; ++v)
            m[u][v] *= invf * outScale(u, v);

    // WG covers block-rows irowA = 2*wg (threads 0-127, a=0) and irowA+1
    // (threads 128-255, a=1); same batch b. Output rows i0, i0+1 of a
    // c-plane are 1 KiB contiguous.
    const int a  = tid >> 7;          // which of the WG's two block-rows
    const int w  = tid >> 6;          // wave id 0..3
    const int l  = tid & 63;          // lane
    const int i0 = (wg << 1) & 127;   // even plane row

    // dst for lane l: float4 #l of the 1 KiB (c, i0..i0+1, j) segment.
    float* dstbase = out + ((size_t)b << 20) + (size_t)i0 * 128 + (l << 2);

    #pragma unroll
    for (int phase = 0; phase < 2; ++phase) {
        if (phase) __syncthreads();   // stores of phase 0 done reading LDS

        // Write this thread's 32 coeffs with c in [phase*32, phase*32+32).
        // addr = c_local*256 + a*128 + j -> bank = j%32: conflict-free.
        #pragma unroll
        for (int u = phase * 4; u < phase * 4 + 4; ++u)
            #pragma unroll
            for (int v = 0; v < 8; ++v)
                lds[(u * 8 + v - phase * 32) * 256 + a * 128 + j] = m[u][v];
        __syncthreads();

        // Each wave stores 8 planes: one instr = one dense 1 KiB burst
        // (64 lanes x float4 covering rows i0 and i0+1 of plane c).
        #pragma unroll
        for (int k = 0; k < 8; ++k) {
            const int cl = w * 8 + k;            // local plane 0..31
            const int c  = phase * 32 + cl;      // global channel
            *reinterpret_cast<float4*>(dstbase + (size_t)c * 16384) =
                *reinterpret_cast<const float4*>(&lds[cl * 256 + (l << 2)]);
        }
    }
}

extern "C" void kernel_launch(void* const* d_in, const int* in_sizes, int n_in,
                              void* d_out, int out_size, void* d_ws, size_t ws_size,
                              hipStream_t stream) {
    const float* img = (const float*)d_in[0];   // 16*1024*1024 fp32
    const float* qfv = (const float*)d_in[1];   // 16 fp32
    float* out = (float*)d_out;                 // 16*64*128*128 fp32

    // 16*128*128 = 262144 blocks, one thread each; 256 threads/WG -> 1024 WGs.
    jpeg_dct_quant_kernel<<<1024, 256, 0, stream>>>(img, qfv, out);
}